// Round 6
// baseline (884.507 us; speedup 1.0000x reference)
//
#include <hip/hip_runtime.h>
#include <hip/hip_fp16.h>
#include <stdint.h>

typedef _Float16 f16;
typedef _Float16 f16x8 __attribute__((ext_vector_type(8)));
typedef float f32x4 __attribute__((ext_vector_type(4)));

#define NROWS 262144
#define MROWS 16
#define TPB   512
#define GPB   8
#define NBLK  (NROWS / (MROWS * GPB))   // 2048
#define THR   0.9921875f

// workspace (f16)
#define WS_W2FS (768 * 192 * 2)            // tabT [768][192] first
#define WS_W2VA (WS_W2FS + 8 * 16 * 96 * 2)

// LDS map (bytes)
//  counts  f32 [4 tb][16 row][196]   @0      (50176)   phase: zero/scatter/gemm
//  feat    f16 per-wave [16][104]    @0      (26624)   phase: epilogue (counts dead)
//  exch    f32 [2 buf][512]          @50176  (4096)
//  prodrow f32 [4][16]               @54272  (256)
#define CNT_STRIDE 196
#define TB_FLOATS  (16 * CNT_STRIDE)       // 3136
#define EXCH_B 50176
#define PROW_B 54272
#define SMEM_SZ 54528

__device__ __forceinline__ f16x8 bc8(uint4 u) {
  union { uint4 u; f16x8 h; } x; x.u = u; return x.h;
}
__device__ __forceinline__ float clampv(float x) {
  return fminf(fmaxf(x, -THR), THR);
}
__device__ __forceinline__ uint32_t pk2(float a, float b) {
  union { __half2 h; uint32_t u; } c; c.h = __floats2half2_rn(a, b); return c.u;
}
__device__ __forceinline__ uint32_t pkrtz(float a, float b) {
  union { decltype(__builtin_amdgcn_cvt_pkrtz(0.f, 0.f)) h; uint32_t u; } c;
  c.h = __builtin_amdgcn_cvt_pkrtz(a, b);
  return c.u;
}
__device__ __forceinline__ uint4 ldfrag(const float* p) {
  float4 x = *(const float4*)p;
  float4 y = *(const float4*)(p + 4);
  uint4 r;
  r.x = pkrtz(x.x, x.y); r.y = pkrtz(x.z, x.w);
  r.z = pkrtz(y.x, y.y); r.w = pkrtz(y.z, y.w);
  return r;
}

// ---------------- prepack ----------------------------------------------------
__global__ void prepack(const float* __restrict__ emb_fs, const float* __restrict__ emb_va,
                        const float* __restrict__ emb_ha, const float* __restrict__ emb_ra,
                        const float* __restrict__ fs_w,   const float* __restrict__ absva_w,
                        const float* __restrict__ absha_w,const float* __restrict__ absra_w,
                        const float* __restrict__ va_w,   const float* __restrict__ fsxva_w,
                        const float* __restrict__ haxra_w, f16* __restrict__ ws) {
  if (blockIdx.x < 24) {                        // tabT transpose, 32-u tiles
    __shared__ float tile[192 * 33];
    int u0 = blockIdx.x * 32;
    int t = threadIdx.x;
    #pragma unroll 4
    for (int i = 0; i < 24; ++i) {
      int idx = t + 256 * i;
      int k = idx >> 5, c = idx & 31, u = u0 + c;
      float v = 0.f;
      if (k < 185) {
        if      (u < 256) v = emb_fs[k * 256 + u];
        else if (u < 512) v = emb_va[k * 256 + (u - 256)];
        else if (u < 640) v = emb_ha[k * 128 + (u - 512)];
        else              v = emb_ra[k * 128 + (u - 640)];
      }
      tile[k * 33 + c] = v;
    }
    __syncthreads();
    #pragma unroll 4
    for (int i = 0; i < 24; ++i) {
      int idx = t + 256 * i;
      int u = idx / 192, k = idx % 192;
      ws[(u0 + u) * 192 + k] = (f16)tile[k * 33 + u];
    }
  } else {                                      // per-wave-slice layer-2 packs
    int gid = (blockIdx.x - 24) * 256 + threadIdx.x;   // 0..24575
    if (gid < 12288) {
      int w = gid / 1536, rem = gid % 1536, j = rem / 96, k = rem % 96;
      float v = (k < 32) ? fs_w[j * 256 + 32 * w + k]
              : (k < 64) ? absva_w[j * 256 + 32 * w + (k - 32)]
              : (k < 80) ? absha_w[j * 128 + 16 * w + (k - 64)]
                         : absra_w[j * 128 + 16 * w + (k - 80)];
      ((f16*)((char*)ws + WS_W2FS))[w * 1536 + j * 96 + k] = (f16)v;
    } else {
      int g2 = gid - 12288;
      int w = g2 / 1536, rem = g2 % 1536, j = rem / 96, k = rem % 96;
      float v = (k < 32) ? va_w[j * 256 + 32 * w + k]
              : (k < 64) ? fsxva_w[j * 256 + 32 * w + (k - 32)]
              : (k < 80) ? haxra_w[j * 128 + 16 * w + (k - 64)]
                         : 0.f;
      ((f16*)((char*)ws + WS_W2VA))[w * 1536 + j * 96 + k] = (f16)v;
    }
  }
}

// ---------------- main fused kernel ------------------------------------------
__global__ __launch_bounds__(TPB, 2)
void rengar_main(const int* __restrict__ pst_idx, const float* __restrict__ color_sign,
                 const float* __restrict__ sob_sign, const float* __restrict__ wtm,
                 const float* __restrict__ tempo_w, const float* __restrict__ fs_b,
                 const float* __restrict__ out_va_w, const float* __restrict__ out_fsxva_w,
                 const f16* __restrict__ ws, float* __restrict__ out) {
  __shared__ __align__(16) char smem[SMEM_SZ];

  const int tid  = threadIdx.x;
  const int lane = tid & 63;
  const int w    = tid >> 6;          // wave 0..7
  const int l15  = lane & 15;
  const int q    = lane >> 4;

  const f16* tabT = ws;

  // wave tile ownership: fs {2w,2w+1}, va {16+2w,17+2w}, ha {32+w}, ra {40+w}
  uint4 afrA[6], afrB[6], afrC[6], afrD[6];
  {
    const f16* pA = tabT + ((size_t)(32 * w + l15)) * 192 + q * 8;
    const f16* pB = tabT + ((size_t)(32 * w + 16 + l15)) * 192 + q * 8;
    const f16* pC = tabT + ((size_t)(256 + 32 * w + l15)) * 192 + q * 8;
    const f16* pD = tabT + ((size_t)(256 + 32 * w + 16 + l15)) * 192 + q * 8;
    #pragma unroll
    for (int ks = 0; ks < 6; ++ks) {
      afrA[ks] = *(const uint4*)(pA + ks * 32);
      afrB[ks] = *(const uint4*)(pB + ks * 32);
      afrC[ks] = *(const uint4*)(pC + ks * 32);
      afrD[ks] = *(const uint4*)(pD + ks * 32);
    }
  }
  // layer-2 per-wave A slices
  uint4 a2f[3], a2v[3];
  {
    const f16* wf = (const f16*)((const char*)ws + WS_W2FS) + w * 1536 + l15 * 96 + q * 8;
    const f16* wv = (const f16*)((const char*)ws + WS_W2VA) + w * 1536 + l15 * 96 + q * 8;
    #pragma unroll
    for (int ks = 0; ks < 3; ++ks) {
      a2f[ks] = *(const uint4*)(wf + ks * 32);
      a2v[ks] = *(const uint4*)(wv + ks * 32);
    }
  }
  float4 tw0 = *(const float4*)(tempo_w + 32 * w + q * 4);
  float4 tw1 = *(const float4*)(tempo_w + 32 * w + 16 + q * 4);

  float bj = 0.f, w1j = 0.f, w2j = 0.f;
  if (tid < 256) {
    int j = tid >> 4;
    bj  = fs_b[j];
    w1j = out_va_w[j];
    w2j = out_fsxva_w[j];
  }

  const int ebase = blockIdx.x * GPB * 512;
  int   vidx = pst_idx[ebase + tid];
  float cc   = color_sign[ebase + tid];
  float ss   = sob_sign[ebase + tid];
  float wtr  = wtm[blockIdx.x * GPB * MROWS + l15];

  char* fb = smem + w * 3328;          // wave-private feature scratch (overlaps counts)

  #pragma unroll 1
  for (int g = 0; g < GPB; ++g) {
    const int r0  = (blockIdx.x * GPB + g) * MROWS;
    const int buf = g & 1;

    // ---- zero counts (3136 uint4) + this group's exch buffer (128 uint4)
    {
      uint4 z = make_uint4(0, 0, 0, 0);
      #pragma unroll
      for (int it = 0; it < 7; ++it) {
        int i = tid + 512 * it;
        if (i < 3264) {
          char* d = (i < 3136) ? smem + i * 16
                               : smem + EXCH_B + buf * 2048 + (i - 3136) * 16;
          *(uint4*)d = z;
        }
      }
    }
    __syncthreads();                               // bar A: zero done

    // ---- store previous group's output
    if (g > 0 && tid < 16) {
      const float* pr = (const float*)(smem + PROW_B);
      out[r0 - MROWS + tid] = pr[tid] + pr[16 + tid] + pr[32 + tid] + pr[48 + tid];
    }

    // ---- scatter: f32 LDS atomics (ds_add_f32)
    {
      float* cnt = (float*)smem;
      int row = tid >> 5;
      int idx = row * CNT_STRIDE + vidx;
      float cs = cc * ss;
      atomicAdd(cnt + idx + 0 * TB_FLOATS, 1.f);
      atomicAdd(cnt + idx + 1 * TB_FLOATS, cc);
      atomicAdd(cnt + idx + 2 * TB_FLOATS, ss);
      atomicAdd(cnt + idx + 3 * TB_FLOATS, cs);
    }
    // prefetch next group's inputs
    float nwt = wtr;
    if (g + 1 < GPB) {
      int nb = ebase + (g + 1) * 512;
      vidx = pst_idx[nb + tid];
      cc   = color_sign[nb + tid];
      ss   = sob_sign[nb + tid];
      nwt  = wtm[r0 + MROWS + l15];
    }
    __syncthreads();                               // bar B: scatter done

    // ---- layer-1 GEMM: A register-resident, B converted f32->f16 in regs
    f32x4 acc0 = {0,0,0,0}, acc1 = {0,0,0,0}, acc2 = {0,0,0,0},
          acc3 = {0,0,0,0}, acc4 = {0,0,0,0}, acc5 = {0,0,0,0};
    {
      const f16* pE = tabT + ((size_t)(512 + 16 * w + l15)) * 192 + q * 8;
      const f16* pF = tabT + ((size_t)(640 + 16 * w + l15)) * 192 + q * 8;
      uint4 afrE[6], afrF[6];
      #pragma unroll
      for (int ks = 0; ks < 6; ++ks) {
        afrE[ks] = *(const uint4*)(pE + ks * 32);
        afrF[ks] = *(const uint4*)(pF + ks * 32);
      }
      const float* cbase = (const float*)smem + l15 * CNT_STRIDE + q * 8;
      uint4 bfr[6];
      #pragma unroll
      for (int ks = 0; ks < 6; ++ks) bfr[ks] = ldfrag(cbase + ks * 32);
      #pragma unroll
      for (int ks = 0; ks < 6; ++ks) {
        acc0 = __builtin_amdgcn_mfma_f32_16x16x32_f16(bc8(afrA[ks]), bc8(bfr[ks]), acc0, 0, 0, 0);
        acc1 = __builtin_amdgcn_mfma_f32_16x16x32_f16(bc8(afrB[ks]), bc8(bfr[ks]), acc1, 0, 0, 0);
      }
      #pragma unroll
      for (int ks = 0; ks < 6; ++ks) bfr[ks] = ldfrag(cbase + 1 * TB_FLOATS + ks * 32);
      #pragma unroll
      for (int ks = 0; ks < 6; ++ks) {
        acc2 = __builtin_amdgcn_mfma_f32_16x16x32_f16(bc8(afrC[ks]), bc8(bfr[ks]), acc2, 0, 0, 0);
        acc3 = __builtin_amdgcn_mfma_f32_16x16x32_f16(bc8(afrD[ks]), bc8(bfr[ks]), acc3, 0, 0, 0);
      }
      #pragma unroll
      for (int ks = 0; ks < 6; ++ks) bfr[ks] = ldfrag(cbase + 2 * TB_FLOATS + ks * 32);
      #pragma unroll
      for (int ks = 0; ks < 6; ++ks)
        acc4 = __builtin_amdgcn_mfma_f32_16x16x32_f16(bc8(afrE[ks]), bc8(bfr[ks]), acc4, 0, 0, 0);
      #pragma unroll
      for (int ks = 0; ks < 6; ++ks) bfr[ks] = ldfrag(cbase + 3 * TB_FLOATS + ks * 32);
      #pragma unroll
      for (int ks = 0; ks < 6; ++ks)
        acc5 = __builtin_amdgcn_mfma_f32_16x16x32_f16(bc8(afrF[ks]), bc8(bfr[ks]), acc5, 0, 0, 0);
    }
    __syncthreads();                               // bar G: all count reads done

    // ---- epilogue: features in regs, layer-2 via wave-private LDS (no barriers)
    float a0[4], a1[4], b0[4], b1[4], hh[4], rr[4];
    {
      float twa[4] = {tw0.x, tw0.y, tw0.z, tw0.w};
      float twb[4] = {tw1.x, tw1.y, tw1.z, tw1.w};
      #pragma unroll
      for (int r = 0; r < 4; ++r) {
        a0[r] = clampv(acc0[r]);
        a1[r] = clampv(acc1[r]);
        b0[r] = clampv(acc2[r] + wtr * twa[r]);
        b1[r] = clampv(acc3[r] + wtr * twb[r]);
        hh[r] = clampv(acc4[r]);
        rr[r] = clampv(acc5[r]);
      }
    }
    const int wrbase = l15 * 208 + q * 8;
    // fs-side slice: [a(32) | |b|(32) | |h|(16) | |r|(16)]
    *(uint2*)(fb + wrbase +   0) = make_uint2(pk2(a0[0], a0[1]), pk2(a0[2], a0[3]));
    *(uint2*)(fb + wrbase +  32) = make_uint2(pk2(a1[0], a1[1]), pk2(a1[2], a1[3]));
    *(uint2*)(fb + wrbase +  64) = make_uint2(pk2(fabsf(b0[0]), fabsf(b0[1])), pk2(fabsf(b0[2]), fabsf(b0[3])));
    *(uint2*)(fb + wrbase +  96) = make_uint2(pk2(fabsf(b1[0]), fabsf(b1[1])), pk2(fabsf(b1[2]), fabsf(b1[3])));
    *(uint2*)(fb + wrbase + 128) = make_uint2(pk2(fabsf(hh[0]), fabsf(hh[1])), pk2(fabsf(hh[2]), fabsf(hh[3])));
    *(uint2*)(fb + wrbase + 160) = make_uint2(pk2(fabsf(rr[0]), fabsf(rr[1])), pk2(fabsf(rr[2]), fabsf(rr[3])));
    f32x4 accf = {0, 0, 0, 0};
    #pragma unroll
    for (int ks = 0; ks < 3; ++ks) {
      uint4 b2 = *(const uint4*)(fb + l15 * 208 + ks * 64 + q * 16);
      accf = __builtin_amdgcn_mfma_f32_16x16x32_f16(bc8(a2f[ks]), bc8(b2), accf, 0, 0, 0);
    }
    // va-side slice: [b(32) | ab(32) | hr(16) | 0(16)]
    *(uint2*)(fb + wrbase +   0) = make_uint2(pk2(b0[0], b0[1]), pk2(b0[2], b0[3]));
    *(uint2*)(fb + wrbase +  32) = make_uint2(pk2(b1[0], b1[1]), pk2(b1[2], b1[3]));
    *(uint2*)(fb + wrbase +  64) = make_uint2(pk2(a0[0]*b0[0], a0[1]*b0[1]), pk2(a0[2]*b0[2], a0[3]*b0[3]));
    *(uint2*)(fb + wrbase +  96) = make_uint2(pk2(a1[0]*b1[0], a1[1]*b1[1]), pk2(a1[2]*b1[2], a1[3]*b1[3]));
    *(uint2*)(fb + wrbase + 128) = make_uint2(pk2(hh[0]*rr[0], hh[1]*rr[1]), pk2(hh[2]*rr[2], hh[3]*rr[3]));
    *(uint2*)(fb + wrbase + 160) = make_uint2(0u, 0u);
    f32x4 accv = {0, 0, 0, 0};
    #pragma unroll
    for (int ks = 0; ks < 3; ++ks) {
      uint4 b2 = *(const uint4*)(fb + l15 * 208 + ks * 64 + q * 16);
      accv = __builtin_amdgcn_mfma_f32_16x16x32_f16(bc8(a2v[ks]), bc8(b2), accv, 0, 0, 0);
    }

    // ---- merge split-K partials via LDS f32 atomics
    {
      float* ex = (float*)(smem + EXCH_B + buf * 2048);
      #pragma unroll
      for (int r = 0; r < 4; ++r) {
        int idx = (q * 4 + r) * 16 + l15;
        atomicAdd(ex + idx,       accf[r]);
        atomicAdd(ex + idx + 256, accv[r]);
      }
    }
    __syncthreads();                               // bar C: exch complete

    // ---- reduce: 256 threads -> prodrow
    if (tid < 256) {
      const float* ex = (const float*)(smem + EXCH_B + buf * 2048);
      float f = clampv(ex[tid] + bj);
      float v = clampv(ex[256 + tid]);
      float o = v * w1j + f * v * w2j;
      o += __shfl_xor(o, 16, 64);
      o += __shfl_xor(o, 32, 64);
      if (lane < 16)
        ((float*)(smem + PROW_B))[(tid >> 6) * 16 + lane] = o;
    }
    wtr = nwt;
  }

  __syncthreads();
  if (tid < 16) {
    const float* pr = (const float*)(smem + PROW_B);
    int r0last = (blockIdx.x * GPB + GPB - 1) * MROWS;
    out[r0last + tid] = pr[tid] + pr[16 + tid] + pr[32 + tid] + pr[48 + tid];
  }
}

extern "C" void kernel_launch(void* const* d_in, const int* in_sizes, int n_in,
                              void* d_out, int out_size, void* d_ws, size_t ws_size,
                              hipStream_t stream) {
  const int*   pst_idx     = (const int*)  d_in[0];
  const float* color_sign  = (const float*)d_in[1];
  const float* sob_sign    = (const float*)d_in[2];
  const float* wtm         = (const float*)d_in[3];
  const float* emb_fs      = (const float*)d_in[4];
  const float* emb_va      = (const float*)d_in[5];
  const float* emb_ha      = (const float*)d_in[6];
  const float* emb_ra      = (const float*)d_in[7];
  const float* tempo_w     = (const float*)d_in[8];
  const float* fs_w        = (const float*)d_in[9];
  const float* fs_b        = (const float*)d_in[10];
  const float* absva_w     = (const float*)d_in[11];
  const float* absha_w     = (const float*)d_in[12];
  const float* absra_w     = (const float*)d_in[13];
  const float* va_w        = (const float*)d_in[14];
  const float* fsxva_w     = (const float*)d_in[15];
  const float* haxra_w     = (const float*)d_in[16];
  const float* out_va_w    = (const float*)d_in[17];
  const float* out_fsxva_w = (const float*)d_in[18];
  float* out = (float*)d_out;
  f16* ws = (f16*)d_ws;

  prepack<<<120, 256, 0, stream>>>(emb_fs, emb_va, emb_ha, emb_ra,
                                   fs_w, absva_w, absha_w, absra_w,
                                   va_w, fsxva_w, haxra_w, ws);
  rengar_main<<<NBLK, TPB, 0, stream>>>(pst_idx, color_sign, sob_sign, wtm,
                                        tempo_w, fs_b, out_va_w, out_fsxva_w,
                                        ws, out);
}